// Round 8
// baseline (69.895 us; speedup 1.0000x reference)
//
#include <hip/hip_runtime.h>

#define IMG_H 1024
#define IMG_W 1024
#define IMG_C 3

// Interior: x in [2,1017], 8 px wide x 2 rows per thread, 127 strips per row-pair.
#define SPR 127
#define ROWPAIRS 510                            // y0 = min(2+2*rp, 1019); rows y0, y0+1
#define N_STRIPS (IMG_C * ROWPAIRS * SPR)       // 194,310
#define NB_INT ((N_STRIPS + 255) / 256)         // 760
#define INT_ROWS 1019
#define BND_PER_C (5 * 1024 + INT_ROWS * 8)     // 13,272
#define N_BND (IMG_C * BND_PER_C)               // 39,816
#define NB_BND ((N_BND + 255) / 256)            // 156

// ===== packed f16x2 compare-exchange machinery (verified rounds 6-7) =====
typedef _Float16 h2 __attribute__((ext_vector_type(2)));

__device__ __forceinline__ h2 h2min(h2 a, h2 b) { return __builtin_elementwise_min(a, b); }
__device__ __forceinline__ h2 h2max(h2 a, h2 b) { return __builtin_elementwise_max(a, b); }
__device__ __forceinline__ void CEh(h2& a, h2& b) { h2 t = h2min(a, b); b = h2max(a, b); a = t; }

__device__ __forceinline__ h2 pkrtz(float a, float b) {
    auto v = __builtin_amdgcn_cvt_pkrtz(a, b);   // v_cvt_pkrtz_f16_f32
    h2 r;
    __builtin_memcpy(&r, &v, sizeof(r));
    return r;
}

__device__ __forceinline__ void merge22h(const h2* A, const h2* B, h2* out) {
    h2 e0 = h2min(A[0], B[0]), e1 = h2max(A[0], B[0]);
    h2 o0 = h2min(A[1], B[1]), o1 = h2max(A[1], B[1]);
    out[0] = e0;
    out[1] = h2min(o0, e1); out[2] = h2max(o0, e1);
    out[3] = o1;
}

__device__ __forceinline__ void merge33h(const h2* A, const h2* B, h2* out) {
    h2 Ae[2] = {A[0], A[2]}, Be[2] = {B[0], B[2]};
    h2 E[4];
    merge22h(Ae, Be, E);
    h2 O0 = h2min(A[1], B[1]), O1 = h2max(A[1], B[1]);
    out[0] = E[0];
    out[1] = h2min(O0, E[1]); out[2] = h2max(O0, E[1]);
    out[3] = h2min(O1, E[2]); out[4] = h2max(O1, E[2]);
    out[5] = E[3];
}

__device__ __forceinline__ void merge55h(const h2* A, const h2* B, h2* out) {
    h2 Ae[3] = {A[0], A[2], A[4]}, Be[3] = {B[0], B[2], B[4]};
    h2 E[6];
    merge33h(Ae, Be, E);
    h2 Ao[2] = {A[1], A[3]}, Bo[2] = {B[1], B[3]};
    h2 O[4];
    merge22h(Ao, Bo, O);
    out[0] = E[0];
    out[1] = h2min(O[0], E[1]); out[2] = h2max(O[0], E[1]);
    out[3] = h2min(O[1], E[2]); out[4] = h2max(O[1], E[2]);
    out[5] = h2min(O[2], E[3]); out[6] = h2max(O[2], E[3]);
    out[7] = h2min(O[3], E[4]); out[8] = h2max(O[3], E[4]);
    out[9] = E[5];
}

__device__ __forceinline__ void merge1010_midh(const h2* A, const h2* B, h2* mid) {
    h2 Ae[5] = {A[0], A[2], A[4], A[6], A[8]}, Be[5] = {B[0], B[2], B[4], B[6], B[8]};
    h2 E[10];
    merge55h(Ae, Be, E);
    h2 Ao[5] = {A[1], A[3], A[5], A[7], A[9]}, Bo[5] = {B[1], B[3], B[5], B[7], B[9]};
    h2 O[10];
    merge55h(Ao, Bo, O);
    mid[0] = h2min(O[3], E[4]); mid[1] = h2max(O[3], E[4]);
    mid[2] = h2min(O[4], E[5]); mid[3] = h2max(O[4], E[5]);
    mid[4] = h2min(O[5], E[6]); mid[5] = h2max(O[5], E[6]);
}

__device__ __forceinline__ h2 final_medianh(const h2* mid, const h2* c5) {
    const _Float16 hinf = (_Float16)__builtin_inff();
    h2 INF2 = {hinf, hinf};
    h2 Ae[3] = {mid[0], mid[2], mid[4]}, Be[3] = {c5[0], c5[2], c5[4]};
    h2 E[6];
    merge33h(Ae, Be, E);
    h2 Ao[3] = {mid[1], mid[3], mid[5]}, Bo[3] = {c5[1], c5[3], INF2};
    h2 O[6];
    merge33h(Ao, Bo, O);
    return h2min(O[2], E[3]);
}

// Whole-strip median network for one window row (verified rounds 6-7).
__device__ __forceinline__ void strip_medians(const h2 Q[8][5], float* po) {
    h2 MA[10], MB[10], MC[10], MD[10];
    merge55h(Q[0], Q[1], MA);   // {M0, M2}
    merge55h(Q[2], Q[3], MB);   // {M1, M3}
    merge55h(Q[4], Q[5], MC);   // {M2, M4}
    merge55h(Q[6], Q[7], MD);   // {M3, M5}

    h2 midA[6], midB[6], midC[6];
    merge1010_midh(MA, MB, midA);   // {mid01, mid23}
    merge1010_midh(MB, MC, midB);   // {mid12, mid34}
    merge1010_midh(MC, MD, midC);   // {mid23, mid45}

    h2 F1 = final_medianh(midA, Q[4]);   // {px0, px4}
    h2 F2 = final_medianh(midB, Q[1]);   // {px1, px5}
    h2 F3 = final_medianh(midB, Q[6]);   // {px2, px6}
    h2 F4 = final_medianh(midC, Q[3]);   // {px3, px7}

    float2* po2 = (float2*)po;           // 8B aligned
    po2[0] = make_float2((float)F1.x, (float)F2.x);
    po2[1] = make_float2((float)F3.x, (float)F4.x);
    po2[2] = make_float2((float)F1.y, (float)F2.y);
    po2[3] = make_float2((float)F3.y, (float)F4.y);
}

// Insert x into sorted s0<=s1<=s2<=s3 -> sorted out[0..4] (verified round 7).
__device__ __forceinline__ void insert5(h2 x, h2 s0, h2 s1, h2 s2, h2 s3, h2* out) {
    out[0] = h2min(x, s0);
    out[1] = h2max(s0, h2min(x, s1));
    out[2] = h2max(s1, h2min(x, s2));
    out[3] = h2max(s2, h2min(x, s3));
    out[4] = h2max(x, s3);
}

// Force >=4 waves/SIMD (VGPR <= 128): occupancy/liveness hypothesis test.
__global__ __launch_bounds__(256, 4) void median5_kernel(const float* __restrict__ img,
                                                         float* __restrict__ out) {
    const float INF = __builtin_inff();

    if (blockIdx.x >= NB_BND) {
        // ===== interior: 8x2 strips, batched loads, staged liveness =====
        int gid = (blockIdx.x - NB_BND) * 256 + threadIdx.x;
        if (gid >= N_STRIPS) return;
        int xs = gid % SPR;
        int t = gid / SPR;
        int rp = t % ROWPAIRS;
        int c = t / ROWPAIRS;
        int y0 = 2 + 2 * rp;
        if (y0 > 1019) y0 = 1019;       // last pair overlaps rows 1019,1020 (dup write, same value)
        int x0 = 2 + 8 * xs;

        const float* p = img + (size_t)c * IMG_H * IMG_W + (size_t)(y0 - 2) * IMG_W + (x0 - 2);

        // --- batch ALL 18 loads (independent; single vmcnt drain) ---
        float4 L[6][3];
#pragma unroll
        for (int r = 0; r < 6; ++r) {
            const float4* rpnt = (const float4*)(p + r * IMG_W);
            L[r][0] = rpnt[0];
            L[r][1] = rpnt[1];
            L[r][2] = rpnt[2];
        }

        // --- convert to packed cols: R0 (row 0), S (rows 1..4), R5 (row 5) ---
        h2 R0[8], R5[8], S[8][4];
#define PACKROW(DST, RR)                                                    \
        {                                                                   \
            float4 a = L[RR][0], b = L[RR][1], d = L[RR][2];                \
            DST[0] = pkrtz(a.x, b.x); DST[1] = pkrtz(a.y, b.y);             \
            DST[2] = pkrtz(a.z, b.z); DST[3] = pkrtz(a.w, b.w);             \
            DST[4] = pkrtz(b.x, d.x); DST[5] = pkrtz(b.y, d.y);             \
            DST[6] = pkrtz(b.z, d.z); DST[7] = pkrtz(b.w, d.w);             \
        }
        PACKROW(R0, 0)
        PACKROW(R5, 5)
#pragma unroll
        for (int r = 1; r <= 4; ++r) {
            float4 a = L[r][0], b = L[r][1], d = L[r][2];
            S[0][r - 1] = pkrtz(a.x, b.x); S[1][r - 1] = pkrtz(a.y, b.y);
            S[2][r - 1] = pkrtz(a.z, b.z); S[3][r - 1] = pkrtz(a.w, b.w);
            S[4][r - 1] = pkrtz(b.x, d.x); S[5][r - 1] = pkrtz(b.y, d.y);
            S[6][r - 1] = pkrtz(b.z, d.z); S[7][r - 1] = pkrtz(b.w, d.w);
        }
#undef PACKROW

        // --- shared middle sort (5-CE 4-sorter), rows y0-1..y0+2 ---
#pragma unroll
        for (int j = 0; j < 8; ++j) {
            CEh(S[j][0], S[j][1]); CEh(S[j][2], S[j][3]);
            CEh(S[j][0], S[j][2]); CEh(S[j][1], S[j][3]);
            CEh(S[j][1], S[j][2]);
        }

        float* po = out + (size_t)c * IMG_H * IMG_W + (size_t)y0 * IMG_W + x0;

        // Window A: rows y0-2..y0+2 (insert R0), compute+store before touching B.
        {
            h2 QA[8][5];
#pragma unroll
            for (int j = 0; j < 8; ++j)
                insert5(R0[j], S[j][0], S[j][1], S[j][2], S[j][3], QA[j]);
            strip_medians(QA, po);
        }
        // Window B: rows y0-1..y0+3 (insert R5).
        {
            h2 QB[8][5];
#pragma unroll
            for (int j = 0; j < 8; ++j)
                insert5(R5[j], S[j][0], S[j][1], S[j][2], S[j][3], QB[j]);
            strip_medians(QB, po + IMG_W);
        }
    } else {
        // ===== boundary frame FIRST: exact fp32 bitonic-32 (verified rounds 1-7) =====
        int gid = blockIdx.x * 256 + threadIdx.x;
        if (gid >= N_BND) return;
        int c = gid / BND_PER_C;
        int b = gid % BND_PER_C;
        int y, x;
        if (b < 2048) {                 // rows 0,1
            y = b >> 10; x = b & 1023;
        } else if (b < 5120) {          // rows 1021..1023
            int t2 = b - 2048;
            y = 1021 + (t2 >> 10); x = t2 & 1023;
        } else {                        // rows 2..1020, cols {0,1} ∪ {1018..1023}
            int t2 = b - 5120;
            y = 2 + (t2 >> 3);
            int m = t2 & 7;
            x = (m < 2) ? m : (1016 + m);
        }

        const float* p = img + (size_t)c * IMG_H * IMG_W;
        float v[32];
#pragma unroll
        for (int i = 25; i < 32; ++i) v[i] = INF;
#pragma unroll
        for (int dy = -2; dy <= 2; ++dy) {
#pragma unroll
            for (int dx = -2; dx <= 2; ++dx) {
                int yy = y + dy;
                int xx = x + dx;
                bool valid = (yy >= 0) && (yy <= IMG_H - 2) && (xx >= 0) && (xx <= IMG_W - 2);
                int yc = min(max(yy, 0), IMG_H - 1);
                int xc = min(max(xx, 0), IMG_W - 1);
                float val = p[yc * IMG_W + xc];
                v[(dy + 2) * 5 + (dx + 2)] = valid ? val : INF;
            }
        }
#pragma unroll
        for (int k = 2; k <= 32; k <<= 1) {
#pragma unroll
            for (int j = k >> 1; j > 0; j >>= 1) {
#pragma unroll
                for (int i = 0; i < 32; ++i) {
                    int l = i ^ j;
                    if (l > i) {
                        bool up = ((i & k) == 0);
                        float a = v[i];
                        float b2 = v[l];
                        float mn = fminf(a, b2);
                        float mx = fmaxf(a, b2);
                        v[i] = up ? mn : mx;
                        v[l] = up ? mx : mn;
                    }
                }
            }
        }
        int ny = min(y + 2, IMG_H - 2) - max(y - 2, 0) + 1;
        int nx = min(x + 2, IMG_W - 2) - max(x - 2, 0) + 1;
        int n = ny * nx;
        int ilo = (n - 1) >> 1;
        int ihi = n >> 1;
        float lo = 0.0f, hi = 0.0f;
#pragma unroll
        for (int i = 0; i < 13; ++i) {
            if (i == ilo) lo = v[i];
            if (i == ihi) hi = v[i];
        }
        out[(size_t)c * IMG_H * IMG_W + (size_t)y * IMG_W + x] = 0.5f * (lo + hi);
    }
}

extern "C" void kernel_launch(void* const* d_in, const int* in_sizes, int n_in,
                              void* d_out, int out_size, void* d_ws, size_t ws_size,
                              hipStream_t stream) {
    const float* img = (const float*)d_in[0];
    float* out = (float*)d_out;
    dim3 block(256);
    dim3 grid(NB_BND + NB_INT);
    median5_kernel<<<grid, block, 0, stream>>>(img, out);
}